// Round 1
// baseline (217.716 us; speedup 1.0000x reference)
//
#include <hip/hip_runtime.h>
#include <hip/hip_bf16.h>
#include <cstdint>
#include <cstddef>

// Problem constants (from reference setup_inputs)
#define HH   16
#define BB   4
#define NN   4096
#define DD   1024
#define MM   (BB * NN)      // 16384 rows
#define NC   128            // scan chunks
#define LC   32             // chunk length (NC*LC == NN)
#define EPSV 1e-6f

typedef short short8 __attribute__((ext_vector_type(8)));   // 8 x bf16 (4 VGPRs)
typedef float floatx4 __attribute__((ext_vector_type(4)));

__device__ __forceinline__ void async_copy16(const void* g, void* l) {
    __builtin_amdgcn_global_load_lds(
        (const __attribute__((address_space(1))) void*)g,
        (__attribute__((address_space(3))) void*)l, 16, 0, 0);
}

// ---- meta: lam[h] = sigmoid(log_decay[h]); c[h] = dot(qh, kh) -------------
__global__ void k_meta(const float* __restrict__ q, const float* __restrict__ k,
                       const float* __restrict__ ld, float* __restrict__ meta) {
    int tid = threadIdx.x;              // 1024 threads; wave w == head w
    float p = q[tid] * k[tid];
    #pragma unroll
    for (int off = 32; off > 0; off >>= 1) p += __shfl_xor(p, off);
    if ((tid & 63) == 0) meta[16 + (tid >> 6)] = p;
    if (tid < HH) meta[tid] = 1.f / (1.f + expf(-ld[tid]));
}

// ---- W'[i,j] = o_w[i,j] * nw[j]  (bf16) -----------------------------------
__global__ void k_wconv(const float* __restrict__ ow, const float* __restrict__ nw,
                        __hip_bfloat16* __restrict__ wp) {
    size_t i = (size_t)blockIdx.x * 256 + threadIdx.x;   // over D*D
    int j = (int)(i & (DD - 1));
    wp[i] = __float2bfloat16(ow[i] * nw[j]);
}

// ---- pass A: chunk-local scan end values ----------------------------------
__global__ void k_chunk_end(const float* __restrict__ x, const float* __restrict__ meta,
                            float* __restrict__ E) {
    int b = blockIdx.x / NC, c = blockIdx.x % NC;
    int j = threadIdx.x;                 // channel 0..1023
    float lam = meta[j >> 6];
    const float* xp = x + ((size_t)(b * NN + c * LC)) * DD + j;
    float e = 0.f;
    #pragma unroll
    for (int t = 0; t < LC; ++t) e = fmaf(lam, e, xp[(size_t)t * DD]);
    E[(size_t)blockIdx.x * DD + j] = e;
}

// ---- pass B: sequential carry prefix over NC chunks -----------------------
__global__ void k_carry(const float* __restrict__ meta, const float* __restrict__ E,
                        float* __restrict__ P) {
    int g = blockIdx.x * 256 + threadIdx.x;  // 0..4095
    int b = g >> 10, j = g & 1023;
    float lam = meta[j >> 6];
    float lamL = lam;                        // lam^32 via 5 squarings
    lamL *= lamL; lamL *= lamL; lamL *= lamL; lamL *= lamL; lamL *= lamL;
    float p = 0.f;
    for (int c = 0; c < NC; ++c) {
        size_t idx = ((size_t)(b * NC + c)) * DD + j;
        P[idx] = p;                          // carry INTO chunk c
        p = fmaf(lamL, p, E[idx]);
    }
}

// ---- pass C: full scan w/ carry, scale by c_h, bf16 store, row sum-sq -----
__global__ void k_scan(const float* __restrict__ x, const float* __restrict__ meta,
                       const float* __restrict__ P, __hip_bfloat16* __restrict__ obf,
                       float* __restrict__ sumsq) {
    __shared__ float wpart[16];
    int b = blockIdx.x / NC, c = blockIdx.x % NC;
    int j = threadIdx.x;
    int h = j >> 6;
    float lam = meta[h];
    float ch  = meta[16 + h];
    int row0 = b * NN + c * LC;
    const float* xp = x + (size_t)row0 * DD + j;
    float y = P[(size_t)blockIdx.x * DD + j];
    for (int t = 0; t < LC; ++t) {
        y = fmaf(lam, y, xp[(size_t)t * DD]);
        float o = ch * y;
        obf[(size_t)(row0 + t) * DD + j] = __float2bfloat16(o);
        float s = o * o;
        #pragma unroll
        for (int off = 32; off > 0; off >>= 1) s += __shfl_xor(s, off);
        if ((j & 63) == 0) wpart[h] = s;
        __syncthreads();
        if (j == 0) {
            float tot = 0.f;
            #pragma unroll
            for (int wv = 0; wv < 16; ++wv) tot += wpart[wv];
            sumsq[row0 + t] = tot;
        }
        __syncthreads();
    }
}

// ---- GEMM: out[m,i] = rs[m] * sum_j A[m,j] * W'[i,j] ----------------------
// m97-style: 128x128 tile, BK=32, 4 waves (2x2), 4x4 mfma_f32_16x16x32_bf16
__launch_bounds__(256)
__global__ void k_gemm(const __hip_bfloat16* __restrict__ A,
                       const __hip_bfloat16* __restrict__ W,
                       const float* __restrict__ sumsq, float* __restrict__ out) {
    __shared__ __attribute__((aligned(16))) short sA[128 * 32];
    __shared__ __attribute__((aligned(16))) short sB[128 * 32];
    const int tid = threadIdx.x;
    const int l = tid & 63, w = tid >> 6;
    const int wm = w >> 1, wn = w & 1;           // 2x2 wave grid, 64x64 each
    const int bm = blockIdx.x >> 3, bn = blockIdx.x & 7;
    const int m0 = bm * 128, n0 = bn * 128;
    const short* Ag = (const short*)A;
    const short* Wg = (const short*)W;

    floatx4 acc[4][4] = {};
    const int srow = w * 16 + (l >> 2);          // staging row within 64-row slab
    const int scol = (l & 3) * 8;                // staging k offset (elements)

    for (int kt = 0; kt < 32; ++kt) {
        const int k0 = kt * 32;
        #pragma unroll
        for (int i = 0; i < 2; ++i) {
            async_copy16(Ag + (size_t)(m0 + i * 64 + srow) * 1024 + k0 + scol,
                         (char*)sA + i * 4096 + w * 1024);
            async_copy16(Wg + (size_t)(n0 + i * 64 + srow) * 1024 + k0 + scol,
                         (char*)sB + i * 4096 + w * 1024);
        }
        __syncthreads();   // drains vmcnt(0): staging visible
        short8 af[4], bf[4];
        #pragma unroll
        for (int mt = 0; mt < 4; ++mt)
            af[mt] = *(const short8*)(sA + (wm * 64 + mt * 16 + (l & 15)) * 32 + (l >> 4) * 8);
        #pragma unroll
        for (int nt = 0; nt < 4; ++nt)
            bf[nt] = *(const short8*)(sB + (wn * 64 + nt * 16 + (l & 15)) * 32 + (l >> 4) * 8);
        #pragma unroll
        for (int mt = 0; mt < 4; ++mt)
            #pragma unroll
            for (int nt = 0; nt < 4; ++nt)
                acc[mt][nt] = __builtin_amdgcn_mfma_f32_16x16x32_bf16(af[mt], bf[nt], acc[mt][nt], 0, 0, 0);
        __syncthreads();   // all reads done before next staging overwrites
    }

    // epilogue: RMSNorm scale + store. D[m,n]: row = quad*4+reg, col = lane&15
    #pragma unroll
    for (int mt = 0; mt < 4; ++mt) {
        #pragma unroll
        for (int r = 0; r < 4; ++r) {
            int mrow = m0 + wm * 64 + mt * 16 + (l >> 4) * 4 + r;
            float rs = rsqrtf(sumsq[mrow] * (1.f / 1024.f) + EPSV);
            #pragma unroll
            for (int nt = 0; nt < 4; ++nt) {
                int col = n0 + wn * 64 + nt * 16 + (l & 15);
                out[(size_t)mrow * 1024 + col] = acc[mt][nt][r] * rs;
            }
        }
    }
}

extern "C" void kernel_launch(void* const* d_in, const int* in_sizes, int n_in,
                              void* d_out, int out_size, void* d_ws, size_t ws_size,
                              hipStream_t stream) {
    const float* x  = (const float*)d_in[0];
    const float* q  = (const float*)d_in[1];
    const float* k  = (const float*)d_in[2];
    const float* ld = (const float*)d_in[3];
    const float* nw = (const float*)d_in[4];
    const float* ow = (const float*)d_in[5];
    float* out = (float*)d_out;

    char* ws = (char*)d_ws;
    // layout (256B aligned): meta[32]f | sumsq[M]f | E[B*NC*D]f | P[..]f | W' bf16 | O bf16
    float* meta  = (float*)(ws + 0);
    float* sumsq = (float*)(ws + 256);
    float* E     = (float*)(ws + 65792);
    float* P     = (float*)(ws + 2162944);
    __hip_bfloat16* Wp  = (__hip_bfloat16*)(ws + 4260096);
    __hip_bfloat16* Obf = (__hip_bfloat16*)(ws + 6357248);
    // total ws use: 39,911,680 bytes

    k_meta<<<1, 1024, 0, stream>>>(q, k, ld, meta);
    k_wconv<<<(DD * DD) / 256, 256, 0, stream>>>(ow, nw, Wp);
    k_chunk_end<<<BB * NC, 1024, 0, stream>>>(x, meta, E);
    k_carry<<<16, 256, 0, stream>>>(meta, E, P);
    k_scan<<<BB * NC, 1024, 0, stream>>>(x, meta, P, Obf, sumsq);
    k_gemm<<<(MM / 128) * (DD / 128), 256, 0, stream>>>(Obf, Wp, sumsq, out);
}

// Round 2
// 199.939 us; speedup vs baseline: 1.0889x; 1.0889x over previous
//
#include <hip/hip_runtime.h>
#include <hip/hip_bf16.h>
#include <cstdint>
#include <cstddef>

// Problem constants (from reference setup_inputs)
#define HH   16
#define BB   4
#define NN   4096
#define DD   1024
#define MM   (BB * NN)      // 16384 rows
#define NC   128            // scan chunks
#define LC   32             // chunk length (NC*LC == NN)
#define EPSV 1e-6f

typedef short short8 __attribute__((ext_vector_type(8)));   // 8 x bf16 (4 VGPRs)
typedef float floatx4 __attribute__((ext_vector_type(4)));

__device__ __forceinline__ void async_copy16(const void* g, void* l) {
    __builtin_amdgcn_global_load_lds(
        (const __attribute__((address_space(1))) void*)g,
        (__attribute__((address_space(3))) void*)l, 16, 0, 0);
}

// ---- meta: lam[h] = sigmoid(log_decay[h]); c[h] = dot(qh, kh) -------------
__global__ void k_meta(const float* __restrict__ q, const float* __restrict__ k,
                       const float* __restrict__ ld, float* __restrict__ meta) {
    int tid = threadIdx.x;              // 1024 threads; wave w == head w
    float p = q[tid] * k[tid];
    #pragma unroll
    for (int off = 32; off > 0; off >>= 1) p += __shfl_xor(p, off);
    if ((tid & 63) == 0) meta[16 + (tid >> 6)] = p;
    if (tid < HH) meta[tid] = 1.f / (1.f + expf(-ld[tid]));
}

// ---- W'[i,j] = o_w[i,j] * nw[j]  (bf16) -----------------------------------
__global__ void k_wconv(const float* __restrict__ ow, const float* __restrict__ nw,
                        __hip_bfloat16* __restrict__ wp) {
    size_t i = (size_t)blockIdx.x * 256 + threadIdx.x;   // over D*D
    int j = (int)(i & (DD - 1));
    wp[i] = __float2bfloat16(ow[i] * nw[j]);
}

// ---- pass A: chunk-local scan end values ----------------------------------
__global__ void k_chunk_end(const float* __restrict__ x, const float* __restrict__ meta,
                            float* __restrict__ E) {
    int b = blockIdx.x >> 7, c = blockIdx.x & (NC - 1);
    int j = threadIdx.x;                 // channel 0..1023
    float lam = meta[j >> 6];
    const float* xp = x + ((size_t)(b * NN + c * LC)) * DD + j;
    float e = 0.f;
    #pragma unroll
    for (int t = 0; t < LC; ++t) e = fmaf(lam, e, xp[(size_t)t * DD]);
    E[(size_t)blockIdx.x * DD + j] = e;
}

// ---- pass B: parallel (Hillis-Steele) carry prefix over NC chunks ---------
// One block per chain (b, j). Transform per chunk: x -> lamL*x + E_c.
// Inclusive scan of transform composition; carry INTO chunk c is b[c-1].
__global__ void k_carry(const float* __restrict__ meta, const float* __restrict__ E,
                        float* __restrict__ P) {
    __shared__ float sa[NC], sb[NC];
    int chain = blockIdx.x;              // 0..4095
    int b = chain >> 10, j = chain & 1023;
    int c = threadIdx.x;                 // chunk index 0..127
    float lam = meta[j >> 6];
    float lamL = lam;                    // lam^32 via 5 squarings
    lamL *= lamL; lamL *= lamL; lamL *= lamL; lamL *= lamL; lamL *= lamL;
    size_t idx = ((size_t)(b * NC + c)) * DD + j;
    float a = lamL, bv = E[idx];
    sa[c] = a; sb[c] = bv;
    #pragma unroll
    for (int d = 1; d < NC; d <<= 1) {
        __syncthreads();
        float pa = 1.f, pb = 0.f;
        if (c >= d) { pa = sa[c - d]; pb = sb[c - d]; }
        __syncthreads();
        bv = fmaf(a, pb, bv);            // compose: use OLD a
        a  = a * pa;
        sa[c] = a; sb[c] = bv;
    }
    __syncthreads();
    P[idx] = (c == 0) ? 0.f : sb[c - 1];
}

// ---- pass C: full scan w/ carry, scale by c_h, bf16 store, row sum-sq -----
// No block barriers: wave == head; shfl-reduce + one atomicAdd per wave/row.
__global__ void k_scan(const float* __restrict__ x, const float* __restrict__ meta,
                       const float* __restrict__ P, __hip_bfloat16* __restrict__ obf,
                       float* __restrict__ sumsq) {
    int b = blockIdx.x >> 7, c = blockIdx.x & (NC - 1);
    int j = threadIdx.x;
    int h = j >> 6;
    float lam = meta[h];
    float ch  = meta[16 + h];
    int row0 = b * NN + c * LC;
    const float* xp = x + (size_t)row0 * DD + j;
    float y = P[(size_t)blockIdx.x * DD + j];
    for (int t = 0; t < LC; ++t) {
        y = fmaf(lam, y, xp[(size_t)t * DD]);
        float o = ch * y;
        obf[(size_t)(row0 + t) * DD + j] = __float2bfloat16(o);
        float s = o * o;
        #pragma unroll
        for (int off = 32; off > 0; off >>= 1) s += __shfl_xor(s, off);
        if ((j & 63) == 0) atomicAdd(&sumsq[row0 + t], s);
    }
}

// ---- GEMM: out[m,i] = rs[m] * sum_j A[m,j] * W'[i,j] ----------------------
// 128x128 tile, BK=64, 4 waves (2x2), 4x4 mfma_f32_16x16x32_bf16, XOR bank
// swizzle on LDS slots, XCD-aware block remap (bm mod 8 == XCD).
__launch_bounds__(256)
__global__ void k_gemm(const __hip_bfloat16* __restrict__ A,
                       const __hip_bfloat16* __restrict__ W,
                       const float* __restrict__ sumsq, float* __restrict__ out) {
    __shared__ __attribute__((aligned(16))) short sA[128 * 64];
    __shared__ __attribute__((aligned(16))) short sB[128 * 64];
    const int tid = threadIdx.x;
    const int l = tid & 63, w = tid >> 6;
    const int wm = w >> 1, wn = w & 1;           // 2x2 wave grid, 64x64 each
    const int g = blockIdx.x;
    const int bm = g & 127, bn = g >> 7;         // same-bm blocks share XCD
    const int m0 = bm * 128, n0 = bn * 128;
    const short* Ag = (const short*)A;
    const short* Wg = (const short*)W;

    floatx4 acc[4][4] = {};

    // staging geometry: slot s = i*256 + tid covers 16B; row = s>>3,
    // swizzled col-octet c8 = (s&7) ^ (row&7)  (bank-conflict-free reads)
    int srow[4], scol[4];
    #pragma unroll
    for (int i = 0; i < 4; ++i) {
        int s = i * 256 + tid;
        srow[i] = s >> 3;
        scol[i] = ((s & 7) ^ ((s >> 3) & 7)) * 8;
    }

    for (int kt = 0; kt < 16; ++kt) {
        const int k0 = kt * 64;
        #pragma unroll
        for (int i = 0; i < 4; ++i) {
            async_copy16(Ag + (size_t)(m0 + srow[i]) * 1024 + k0 + scol[i],
                         (char*)sA + i * 4096 + w * 1024);
            async_copy16(Wg + (size_t)(n0 + srow[i]) * 1024 + k0 + scol[i],
                         (char*)sB + i * 4096 + w * 1024);
        }
        __syncthreads();   // drains vmcnt(0): staging visible
        #pragma unroll
        for (int ks = 0; ks < 2; ++ks) {
            short8 af[4], bf[4];
            #pragma unroll
            for (int mt = 0; mt < 4; ++mt) {
                int row = wm * 64 + mt * 16 + (l & 15);
                int c8  = (ks * 4 + (l >> 4)) ^ (row & 7);
                af[mt] = *(const short8*)(sA + row * 64 + c8 * 8);
            }
            #pragma unroll
            for (int nt = 0; nt < 4; ++nt) {
                int row = wn * 64 + nt * 16 + (l & 15);
                int c8  = (ks * 4 + (l >> 4)) ^ (row & 7);
                bf[nt] = *(const short8*)(sB + row * 64 + c8 * 8);
            }
            #pragma unroll
            for (int mt = 0; mt < 4; ++mt)
                #pragma unroll
                for (int nt = 0; nt < 4; ++nt)
                    acc[mt][nt] = __builtin_amdgcn_mfma_f32_16x16x32_bf16(af[mt], bf[nt], acc[mt][nt], 0, 0, 0);
        }
        __syncthreads();   // all reads done before next staging overwrites
    }

    // epilogue: RMSNorm scale + store. D[m,n]: row = quad*4+reg, col = lane&15
    #pragma unroll
    for (int mt = 0; mt < 4; ++mt) {
        #pragma unroll
        for (int r = 0; r < 4; ++r) {
            int mrow = m0 + wm * 64 + mt * 16 + (l >> 4) * 4 + r;
            float rs = rsqrtf(sumsq[mrow] * (1.f / 1024.f) + EPSV);
            #pragma unroll
            for (int nt = 0; nt < 4; ++nt) {
                int col = n0 + wn * 64 + nt * 16 + (l & 15);
                out[(size_t)mrow * 1024 + col] = acc[mt][nt][r] * rs;
            }
        }
    }
}

extern "C" void kernel_launch(void* const* d_in, const int* in_sizes, int n_in,
                              void* d_out, int out_size, void* d_ws, size_t ws_size,
                              hipStream_t stream) {
    const float* x  = (const float*)d_in[0];
    const float* q  = (const float*)d_in[1];
    const float* k  = (const float*)d_in[2];
    const float* ld = (const float*)d_in[3];
    const float* nw = (const float*)d_in[4];
    const float* ow = (const float*)d_in[5];
    float* out = (float*)d_out;

    char* ws = (char*)d_ws;
    // layout (256B aligned): meta[32]f | sumsq[M]f | E f | P f | W' bf16 | O bf16
    float* meta  = (float*)(ws + 0);
    float* sumsq = (float*)(ws + 256);
    float* E     = (float*)(ws + 65792);
    float* P     = (float*)(ws + 2162944);
    __hip_bfloat16* Wp  = (__hip_bfloat16*)(ws + 4260096);
    __hip_bfloat16* Obf = (__hip_bfloat16*)(ws + 6357248);
    // total ws use: ~40 MB

    hipMemsetAsync(sumsq, 0, MM * sizeof(float), stream);  // for k_scan atomics
    k_meta<<<1, 1024, 0, stream>>>(q, k, ld, meta);
    k_wconv<<<(DD * DD) / 256, 256, 0, stream>>>(ow, nw, Wp);
    k_chunk_end<<<BB * NC, 1024, 0, stream>>>(x, meta, E);
    k_carry<<<BB * DD, NC, 0, stream>>>(meta, E, P);
    k_scan<<<BB * NC, 1024, 0, stream>>>(x, meta, P, Obf, sumsq);
    k_gemm<<<(MM / 128) * (DD / 128), 256, 0, stream>>>(Obf, Wp, sumsq, out);
}

// Round 3
// 190.184 us; speedup vs baseline: 1.1448x; 1.0513x over previous
//
#include <hip/hip_runtime.h>
#include <hip/hip_bf16.h>
#include <cstdint>
#include <cstddef>

// Problem constants (from reference setup_inputs)
#define HH   16
#define BB   4
#define NN   4096
#define DD   1024
#define MM   (BB * NN)      // 16384 rows
#define NC   128            // scan chunks
#define LC   32             // chunk length (NC*LC == NN)
#define EPSV 1e-6f

typedef short short8 __attribute__((ext_vector_type(8)));   // 8 x bf16 (4 VGPRs)
typedef float floatx4 __attribute__((ext_vector_type(4)));

__device__ __forceinline__ void async_copy16(const void* g, void* l) {
    __builtin_amdgcn_global_load_lds(
        (const __attribute__((address_space(1))) void*)g,
        (__attribute__((address_space(3))) void*)l, 16, 0, 0);
}

__device__ __forceinline__ uint2 pack_bf16x4(float a, float b, float c, float d) {
    union { __hip_bfloat16 h[4]; uint2 u; } cv;
    cv.h[0] = __float2bfloat16(a); cv.h[1] = __float2bfloat16(b);
    cv.h[2] = __float2bfloat16(c); cv.h[3] = __float2bfloat16(d);
    return cv.u;
}

// ---- meta: lam[h] = sigmoid(log_decay[h]); c[h] = dot(qh, kh) -------------
__global__ void k_meta(const float* __restrict__ q, const float* __restrict__ k,
                       const float* __restrict__ ld, float* __restrict__ meta) {
    int tid = threadIdx.x;              // 1024 threads; wave w == head w
    float p = q[tid] * k[tid];
    #pragma unroll
    for (int off = 32; off > 0; off >>= 1) p += __shfl_xor(p, off);
    if ((tid & 63) == 0) meta[16 + (tid >> 6)] = p;
    if (tid < HH) meta[tid] = 1.f / (1.f + expf(-ld[tid]));
}

// ---- W'[i,j] = o_w[i,j] * nw[j]  (bf16), float4 vectorized ---------------
__global__ void k_wconv(const float* __restrict__ ow, const float* __restrict__ nw,
                        __hip_bfloat16* __restrict__ wp) {
    size_t i4 = (size_t)blockIdx.x * 256 + threadIdx.x;  // over D*D/4
    int j = (int)((i4 * 4) & (DD - 1));
    float4 v = ((const float4*)ow)[i4];
    ((uint2*)wp)[i4] = pack_bf16x4(v.x * nw[j], v.y * nw[j + 1],
                                   v.z * nw[j + 2], v.w * nw[j + 3]);
}

// ---- pass A: chunk-local scan end values (float4 per thread) --------------
__global__ void k_chunk_end(const float* __restrict__ x, const float* __restrict__ meta,
                            float* __restrict__ E) {
    int b = blockIdx.x >> 7, c = blockIdx.x & (NC - 1);
    int j4 = threadIdx.x;                // float4 channel group 0..255
    float lam = meta[(j4 * 4) >> 6];     // 4-ch group never crosses a head
    const float4* xp = (const float4*)(x + ((size_t)(b * NN + c * LC)) * DD) + j4;
    float4 e = {0.f, 0.f, 0.f, 0.f};
    #pragma unroll
    for (int t = 0; t < LC; ++t) {
        float4 v = xp[(size_t)t * (DD / 4)];
        e.x = fmaf(lam, e.x, v.x); e.y = fmaf(lam, e.y, v.y);
        e.z = fmaf(lam, e.z, v.z); e.w = fmaf(lam, e.w, v.w);
    }
    ((float4*)(E + (size_t)blockIdx.x * DD))[j4] = e;
}

// ---- pass B: carry prefix via LDS transpose (coalesced global access) -----
// Block handles 32 chains (one b, 32 consecutive channels) over all 128 chunks.
__global__ void k_carry(const float* __restrict__ meta, const float* __restrict__ E,
                        float* __restrict__ P) {
    __shared__ float tile[NC][33];       // +1 pad
    int b = blockIdx.x >> 5, jg = blockIdx.x & 31;   // 4 b x 32 j-groups
    int tid = threadIdx.x;               // 256 threads
    int cc = tid >> 5, jj = tid & 31;
    #pragma unroll
    for (int it = 0; it < 16; ++it) {
        int c = it * 8 + cc;
        tile[c][jj] = E[(size_t)(b * NC + c) * DD + jg * 32 + jj];
    }
    __syncthreads();
    if (tid < 32) {
        int j = jg * 32 + tid;           // 32-ch group never crosses a head
        float lam = meta[j >> 6];
        float lamL = lam;                // lam^32 via 5 squarings
        lamL *= lamL; lamL *= lamL; lamL *= lamL; lamL *= lamL; lamL *= lamL;
        float p = 0.f;
        for (int c = 0; c < NC; ++c) {
            float e = tile[c][tid];
            tile[c][tid] = p;            // carry INTO chunk c
            p = fmaf(lamL, p, e);
        }
    }
    __syncthreads();
    #pragma unroll
    for (int it = 0; it < 16; ++it) {
        int c = it * 8 + cc;
        P[(size_t)(b * NC + c) * DD + jg * 32 + jj] = tile[c][jj];
    }
}

// ---- pass C: full scan w/ carry, scale, bf16 store, row sum-sq (float4) ---
__global__ void k_scan(const float* __restrict__ x, const float* __restrict__ meta,
                       const float* __restrict__ P, __hip_bfloat16* __restrict__ obf,
                       float* __restrict__ sumsq) {
    int b = blockIdx.x >> 7, c = blockIdx.x & (NC - 1);
    int j4 = threadIdx.x;                // 0..255
    int h = (j4 * 4) >> 6;
    float lam = meta[h];
    float ch  = meta[16 + h];
    int row0 = b * NN + c * LC;
    const float4* xp = (const float4*)(x + (size_t)row0 * DD) + j4;
    float4 y = ((const float4*)(P + (size_t)blockIdx.x * DD))[j4];
    int lane0 = ((threadIdx.x & 63) == 0);
    for (int t = 0; t < LC; ++t) {
        float4 v = xp[(size_t)t * (DD / 4)];
        y.x = fmaf(lam, y.x, v.x); y.y = fmaf(lam, y.y, v.y);
        y.z = fmaf(lam, y.z, v.z); y.w = fmaf(lam, y.w, v.w);
        float ox = ch * y.x, oy = ch * y.y, oz = ch * y.z, ow = ch * y.w;
        ((uint2*)(obf + (size_t)(row0 + t) * DD))[j4] = pack_bf16x4(ox, oy, oz, ow);
        float s = ox * ox + oy * oy + oz * oz + ow * ow;   // full-row sum: no head split
        #pragma unroll
        for (int off = 32; off > 0; off >>= 1) s += __shfl_xor(s, off);
        if (lane0) atomicAdd(&sumsq[row0 + t], s);
    }
}

// ---- GEMM: out[m,i] = rs[m] * sum_j A[m,j] * W'[i,j] ----------------------
// 128x128 tile, BK=64, 4 waves (2x2), 4x4 mfma_f32_16x16x32_bf16, XOR bank
// swizzle on LDS slots, XCD-aware block remap (bm mod 8 == XCD).
__launch_bounds__(256)
__global__ void k_gemm(const __hip_bfloat16* __restrict__ A,
                       const __hip_bfloat16* __restrict__ W,
                       const float* __restrict__ sumsq, float* __restrict__ out) {
    __shared__ __attribute__((aligned(16))) short sA[128 * 64];
    __shared__ __attribute__((aligned(16))) short sB[128 * 64];
    const int tid = threadIdx.x;
    const int l = tid & 63, w = tid >> 6;
    const int wm = w >> 1, wn = w & 1;           // 2x2 wave grid, 64x64 each
    const int g = blockIdx.x;
    const int bm = g & 127, bn = g >> 7;         // same-bm blocks share XCD
    const int m0 = bm * 128, n0 = bn * 128;
    const short* Ag = (const short*)A;
    const short* Wg = (const short*)W;

    floatx4 acc[4][4] = {};

    // staging geometry: slot s = i*256 + tid covers 16B; row = s>>3,
    // swizzled col-octet c8 = (s&7) ^ (row&7)  (bank-conflict-free reads)
    int srow[4], scol[4];
    #pragma unroll
    for (int i = 0; i < 4; ++i) {
        int s = i * 256 + tid;
        srow[i] = s >> 3;
        scol[i] = ((s & 7) ^ ((s >> 3) & 7)) * 8;
    }

    for (int kt = 0; kt < 16; ++kt) {
        const int k0 = kt * 64;
        #pragma unroll
        for (int i = 0; i < 4; ++i) {
            async_copy16(Ag + (size_t)(m0 + srow[i]) * 1024 + k0 + scol[i],
                         (char*)sA + i * 4096 + w * 1024);
            async_copy16(Wg + (size_t)(n0 + srow[i]) * 1024 + k0 + scol[i],
                         (char*)sB + i * 4096 + w * 1024);
        }
        __syncthreads();   // drains vmcnt(0): staging visible
        #pragma unroll
        for (int ks = 0; ks < 2; ++ks) {
            short8 af[4], bf[4];
            #pragma unroll
            for (int mt = 0; mt < 4; ++mt) {
                int row = wm * 64 + mt * 16 + (l & 15);
                int c8  = (ks * 4 + (l >> 4)) ^ (row & 7);
                af[mt] = *(const short8*)(sA + row * 64 + c8 * 8);
            }
            #pragma unroll
            for (int nt = 0; nt < 4; ++nt) {
                int row = wn * 64 + nt * 16 + (l & 15);
                int c8  = (ks * 4 + (l >> 4)) ^ (row & 7);
                bf[nt] = *(const short8*)(sB + row * 64 + c8 * 8);
            }
            #pragma unroll
            for (int mt = 0; mt < 4; ++mt)
                #pragma unroll
                for (int nt = 0; nt < 4; ++nt)
                    acc[mt][nt] = __builtin_amdgcn_mfma_f32_16x16x32_bf16(af[mt], bf[nt], acc[mt][nt], 0, 0, 0);
        }
        __syncthreads();   // all reads done before next staging overwrites
    }

    // epilogue: RMSNorm scale + store. D[m,n]: row = quad*4+reg, col = lane&15
    #pragma unroll
    for (int mt = 0; mt < 4; ++mt) {
        #pragma unroll
        for (int r = 0; r < 4; ++r) {
            int mrow = m0 + wm * 64 + mt * 16 + (l >> 4) * 4 + r;
            float rs = rsqrtf(sumsq[mrow] * (1.f / 1024.f) + EPSV);
            #pragma unroll
            for (int nt = 0; nt < 4; ++nt) {
                int col = n0 + wn * 64 + nt * 16 + (l & 15);
                out[(size_t)mrow * 1024 + col] = acc[mt][nt][r] * rs;
            }
        }
    }
}

extern "C" void kernel_launch(void* const* d_in, const int* in_sizes, int n_in,
                              void* d_out, int out_size, void* d_ws, size_t ws_size,
                              hipStream_t stream) {
    const float* x  = (const float*)d_in[0];
    const float* q  = (const float*)d_in[1];
    const float* k  = (const float*)d_in[2];
    const float* ld = (const float*)d_in[3];
    const float* nw = (const float*)d_in[4];
    const float* ow = (const float*)d_in[5];
    float* out = (float*)d_out;

    char* ws = (char*)d_ws;
    // layout (256B aligned): meta[32]f | sumsq[M]f | E f | P f | W' bf16 | O bf16
    float* meta  = (float*)(ws + 0);
    float* sumsq = (float*)(ws + 256);
    float* E     = (float*)(ws + 65792);
    float* P     = (float*)(ws + 2162944);
    __hip_bfloat16* Wp  = (__hip_bfloat16*)(ws + 4260096);
    __hip_bfloat16* Obf = (__hip_bfloat16*)(ws + 6357248);
    // total ws use: ~40 MB

    hipMemsetAsync(sumsq, 0, MM * sizeof(float), stream);  // for k_scan atomics
    k_meta<<<1, 1024, 0, stream>>>(q, k, ld, meta);
    k_wconv<<<(DD * DD / 4) / 256, 256, 0, stream>>>(ow, nw, Wp);
    k_chunk_end<<<BB * NC, 256, 0, stream>>>(x, meta, E);
    k_carry<<<BB * 32, 256, 0, stream>>>(meta, E, P);
    k_scan<<<BB * NC, 256, 0, stream>>>(x, meta, P, Obf, sumsq);
    k_gemm<<<(MM / 128) * (DD / 128), 256, 0, stream>>>(Obf, Wp, sumsq, out);
}